// Round 12
// baseline (461.152 us; speedup 1.0000x reference)
//
#include <hip/hip_runtime.h>

#define B_ROWS 16384
#define L1DIM  3072
#define NOUT1  16
#define NCOUNT 8
#define CORR   0.9921875f   // 127/128

// ws layout (bytes):
#define WS_PARTIAL 0          // 32*8*4 = 1024
#define WS_OFFS    1024       // 9*4 -> pad 64
#define WS_CUR     1088       // 8*4 -> pad 64
#define WS_W1C     1152       // 8*16*3072*4 = 1572864
#define WS_SORTED  1574016    // 16384*4 = 65536

// ---------------------------------------------------------------------------
// W1c[s][o][k] = W1_stack[s][o][k] + W1_factor[o][k]
// ---------------------------------------------------------------------------
__global__ void prep_w1(const float* __restrict__ W1_stack,
                        const float* __restrict__ W1_factor,
                        float* __restrict__ W1c) {
    int v = blockIdx.x * 256 + threadIdx.x;        // float4 index
    const float4* S = (const float4*)W1_stack;
    const float4* F = (const float4*)W1_factor;
    float4 a = S[v];
    float4 b = F[v % 12288];                       // 16*3072/4 per stack
    float4 r;
    r.x = a.x + b.x; r.y = a.y + b.y; r.z = a.z + b.z; r.w = a.w + b.w;
    ((float4*)W1c)[v] = r;
}

// ---------------------------------------------------------------------------
// Bucketing: count -> scan -> scatter   (unchanged, pass-verified R1-R3)
// ---------------------------------------------------------------------------
__global__ void bucket_count(const int* __restrict__ ls,
                             int* __restrict__ partial) {
    __shared__ int cnt[NCOUNT];
    if (threadIdx.x < NCOUNT) cnt[threadIdx.x] = 0;
    __syncthreads();
    for (int i = blockIdx.x * 256 + threadIdx.x; i < B_ROWS; i += 32 * 256)
        atomicAdd(&cnt[ls[i]], 1);
    __syncthreads();
    if (threadIdx.x < NCOUNT)
        partial[blockIdx.x * NCOUNT + threadIdx.x] = cnt[threadIdx.x];
}

__global__ void bucket_scan(const int* __restrict__ partial,
                            int* __restrict__ offsets,
                            int* __restrict__ cur) {
    __shared__ int tot[NCOUNT];
    int k = threadIdx.x;
    if (k < NCOUNT) {
        int t = 0;
        #pragma unroll
        for (int b = 0; b < 32; ++b) t += partial[b * NCOUNT + k];
        tot[k] = t;
    }
    __syncthreads();
    if (k == 0) {
        int run = 0;
        #pragma unroll
        for (int j = 0; j < NCOUNT; ++j) {
            offsets[j] = run; cur[j] = run; run += tot[j];
        }
        offsets[NCOUNT] = run;
    }
}

__global__ void bucket_scatter(const int* __restrict__ ls,
                               int* __restrict__ cur,
                               int* __restrict__ sorted) {
    int lane = threadIdx.x & 63;
    for (int i = blockIdx.x * 256 + threadIdx.x; i < B_ROWS; i += 32 * 256) {
        int v = ls[i];
        #pragma unroll
        for (int k = 0; k < NCOUNT; ++k) {
            unsigned long long m = __ballot(v == k);
            if (m) {
                int leader = __ffsll((unsigned long long)m) - 1;
                int base = 0;
                if (v == k && lane == leader)
                    base = atomicAdd(&cur[k], __popcll(m));
                base = __shfl(base, leader);
                if (v == k) {
                    int rank = __popcll(m & ((1ull << lane) - 1ull));
                    sorted[base + rank] = i;
                }
            }
        }
    }
}

// Counted-vmcnt barrier: waits only until <=N VMEM ops outstanding, then
// block barrier. The fresh prefetch groups (8 newest ops) stay in flight
// across the barrier -- this is the T3/T4 pattern, avoiding the vmcnt(0)
// drain that __syncthreads forces.
#define WAITBAR(N) do {                                        \
    asm volatile("s_waitcnt vmcnt(" #N ")" ::: "memory");      \
    __builtin_amdgcn_s_barrier();                              \
    __builtin_amdgcn_sched_barrier(0);                         \
} while (0)

// ---------------------------------------------------------------------------
// Main fused kernel. Block = 256 thr = 4 waves; 16 rows/block, J=2 rows/lane
// (R2-verified geometry). W chunks (16 outs x 128 k = 8KB) staged via
// global_load_lds into a 4-deep LDS ring, stage distance 2; x double-slot
// ring 2 chunks ahead in registers. One raw barrier + vmcnt(8) per chunk.
// Safety: buffer b[(t+2)%4] was last read at iter t-2; passing the t-1
// barrier guarantees all waves finished that read before this stage lands.
// ---------------------------------------------------------------------------
__global__ __launch_bounds__(256, 3)
void ls_main(const float* __restrict__ x,
             const float* __restrict__ W1c,
             const float* __restrict__ b1,
             const float* __restrict__ W2,
             const float* __restrict__ b2,
             const float* __restrict__ W3,
             const float* __restrict__ b3,
             const int* __restrict__ offsets,
             const int* __restrict__ sorted,
             float* __restrict__ out) {
    const int SEGSHIFT = 10;                 // 1024 segs per bucket (worst case)
    int s   = blockIdx.x >> SEGSHIFT;
    int seg = blockIdx.x & ((1 << SEGSHIFT) - 1);
    int bstart = offsets[s];
    int bend   = offsets[s + 1];
    int start  = bstart + seg * 16;          // 16 rows per block
    if (start >= bend) return;               // uniform early exit (pre-barrier)

    __shared__ float wlds[4][NOUT1 * 128];   // 4 x 8KB ring

    int tid  = threadIdx.x;
    int wv   = tid >> 6;
    int lane = tid & 63;
    int rg   = lane >> 5;                    // 0..1
    int g    = lane & 31;                    // K-stripe
    int gb   = g << 2;

    int rowbase = start + wv * 4 + rg * 2;   // 2 rows per lane
    int rid[2];
    const float* xp[2];
    #pragma unroll
    for (int j = 0; j < 2; ++j) {
        int p = rowbase + j;
        int r = (p < bend) ? sorted[p] : 0;
        rid[j] = (p < bend) ? r : -1;
        xp[j]  = x + (size_t)r * L1DIM + gb;
    }
    const float* Ws = W1c + (size_t)s * (NOUT1 * L1DIM);

    float acc[2][16];
    #pragma unroll
    for (int j = 0; j < 2; ++j)
        #pragma unroll
        for (int o = 0; o < 16; ++o) acc[j][o] = 0.0f;

    float4 xs0[2], xs1[2], xs2[2], xs3[2];   // x ring, static slots

    auto LOADX = [&](float4 (&d)[2], int c) {
        int k = c << 7;
        d[0] = *(const float4*)(xp[0] + k);
        d[1] = *(const float4*)(xp[1] + k);
    };
    // Stage 8KB W chunk into wlds[b]: each wave issues 2 global_load_lds of
    // 1KB (2 o-rows each). Linear LDS dst (wave-uniform base + lane*16).
    // Layout verified in R3 (passed refcheck).
    auto STAGEW = [&](int b, int c) {
        int kc = c << 7;
        #pragma unroll
        for (int q = 0; q < 2; ++q) {
            int opair = (wv << 2) + (q << 1);
            int o2    = opair + (lane >> 5);
            const float* src = Ws + (size_t)o2 * L1DIM + kc + ((lane & 31) << 2);
            float* dst = &wlds[b][opair * 128];
            __builtin_amdgcn_global_load_lds(
                (const __attribute__((address_space(1))) void*)src,
                (__attribute__((address_space(3))) void*)dst,
                16, 0, 0);
        }
    };
    auto COMPUTE = [&](int b, const float4 (&xv)[2]) {
        #pragma unroll
        for (int og = 0; og < 2; ++og) {
            float4 w[8];
            #pragma unroll
            for (int oo = 0; oo < 8; ++oo)
                w[oo] = *(const float4*)&wlds[b][(og * 8 + oo) * 128 + gb];
            #pragma unroll
            for (int oo = 0; oo < 8; ++oo) {
                int o = og * 8 + oo;
                #pragma unroll
                for (int j = 0; j < 2; ++j) {
                    acc[j][o] = fmaf(xv[j].x, w[oo].x,
                                 fmaf(xv[j].y, w[oo].y,
                                  fmaf(xv[j].z, w[oo].z,
                                   fmaf(xv[j].w, w[oo].w, acc[j][o]))));
                }
            }
        }
    };

    // prologue: chunk 0 -> (b0, xs0), chunk 1 -> (b1, xs1). 8 VMEM in flight.
    LOADX(xs0, 0); STAGEW(0, 0);
    LOADX(xs1, 1); STAGEW(1, 1);

    // main: t = 4*mo + u, chunks 0..19 consumed, prefetch t+2 (chunks 2..21).
    // At each WAITBAR(8): outstanding = {t group, t-1 group} = 8 ops; chunk-t
    // stage + x (issued at t-2) are drained. Asm "memory" pins group order.
    #pragma unroll 1
    for (int mo = 0; mo < 5; ++mo) {
        int t = mo << 2;
        LOADX(xs2, t + 2); STAGEW(2, t + 2);
        WAITBAR(8);
        COMPUTE(0, xs0);
        LOADX(xs3, t + 3); STAGEW(3, t + 3);
        WAITBAR(8);
        COMPUTE(1, xs1);
        LOADX(xs0, t + 4); STAGEW(0, t + 4);
        WAITBAR(8);
        COMPUTE(2, xs2);
        LOADX(xs1, t + 5); STAGEW(1, t + 5);
        WAITBAR(8);
        COMPUTE(3, xs3);
    }
    // tail: chunks 20..23 (prefetch 22,23 then drain)
    LOADX(xs2, 22); STAGEW(2, 22);
    WAITBAR(8);
    COMPUTE(0, xs0);                         // chunk 20
    LOADX(xs3, 23); STAGEW(3, 23);
    WAITBAR(8);
    COMPUTE(1, xs1);                         // chunk 21
    WAITBAR(4);
    COMPUTE(2, xs2);                         // chunk 22
    WAITBAR(0);
    COMPUTE(3, xs3);                         // chunk 23

    // ---- reduce-scatter within each 32-lane rg group (R2-verified) ----
    bool hi4 = (g & 16) != 0;
    float r[16];
    #pragma unroll
    for (int o = 0; o < 16; ++o) {
        float sA = hi4 ? acc[0][o] : acc[1][o];
        float rA = __shfl_xor(sA, 16);
        r[o] = (hi4 ? acc[1][o] : acc[0][o]) + rA;
    }
    #pragma unroll
    for (int o = 0; o < 16; ++o) {
        r[o] += __shfl_xor(r[o], 8);
        r[o] += __shfl_xor(r[o], 4);
        r[o] += __shfl_xor(r[o], 2);
        r[o] += __shfl_xor(r[o], 1);
    }
    int jloc = (g >> 4) & 1;                 // row within this lane's pair
    int sub  = g & 15;                       // 16 lanes per row

    // ---- epilogue: bias, CReLU^2 concat, layer2 (32x30), layer3 (1x32) ----
    const float* b1p = b1 + s * 16;
    float l1c15 = r[15] + b1p[15];           // l1x_out (not clipped)
    float h[30];
    #pragma unroll
    for (int j = 0; j < 15; ++j) {
        float v = r[j] + b1p[j];
        h[j]      = fminf(v * v * CORR, 1.0f);       // sqr branch, >=0
        h[15 + j] = fminf(fmaxf(v, 0.0f), 1.0f);     // linear branch
    }
    float p3 = 0.0f;
    #pragma unroll
    for (int m2 = 0; m2 < 2; ++m2) {
        int o2 = sub + m2 * 16;
        const float2* w2r = (const float2*)(W2 + (size_t)(s * 32 + o2) * 30);
        float a2 = b2[s * 32 + o2];
        #pragma unroll
        for (int jj = 0; jj < 15; ++jj) {
            float2 wv2 = w2r[jj];
            a2 = fmaf(h[2 * jj], wv2.x, fmaf(h[2 * jj + 1], wv2.y, a2));
        }
        a2 = fminf(fmaxf(a2, 0.0f), 1.0f);
        p3 = fmaf(a2, W3[s * 32 + o2], p3);
    }
    p3 += __shfl_xor(p3, 8);
    p3 += __shfl_xor(p3, 4);
    p3 += __shfl_xor(p3, 2);
    p3 += __shfl_xor(p3, 1);

    if (sub == 0 && rid[jloc] >= 0) {
        out[rid[jloc]] = p3 + b3[s] + l1c15;
    }
}

// ---------------------------------------------------------------------------
extern "C" void kernel_launch(void* const* d_in, const int* in_sizes, int n_in,
                              void* d_out, int out_size, void* d_ws, size_t ws_size,
                              hipStream_t stream) {
    const float* x         = (const float*)d_in[0];
    const int*   ls        = (const int*)  d_in[1];
    const float* W1_stack  = (const float*)d_in[2];
    const float* W1_factor = (const float*)d_in[3];
    const float* b1        = (const float*)d_in[4];
    const float* W2        = (const float*)d_in[5];
    const float* b2        = (const float*)d_in[6];
    const float* W3        = (const float*)d_in[7];
    const float* b3        = (const float*)d_in[8];
    float* out = (float*)d_out;

    char* ws = (char*)d_ws;
    int*   partial = (int*)(ws + WS_PARTIAL);
    int*   offs    = (int*)(ws + WS_OFFS);
    int*   cur     = (int*)(ws + WS_CUR);
    float* W1c     = (float*)(ws + WS_W1C);
    int*   sorted  = (int*)(ws + WS_SORTED);

    hipLaunchKernelGGL(prep_w1, dim3(384), dim3(256), 0, stream,
                       W1_stack, W1_factor, W1c);
    hipLaunchKernelGGL(bucket_count, dim3(32), dim3(256), 0, stream,
                       ls, partial);
    hipLaunchKernelGGL(bucket_scan, dim3(1), dim3(64), 0, stream,
                       partial, offs, cur);
    hipLaunchKernelGGL(bucket_scatter, dim3(32), dim3(256), 0, stream,
                       ls, cur, sorted);
    hipLaunchKernelGGL(ls_main, dim3(8 << 10), dim3(256), 0, stream,
                       x, W1c, b1, W2, b2, W3, b3, offs, sorted, out);
}